// Round 5
// baseline (19249.692 us; speedup 1.0000x reference)
//
#include <hip/hip_runtime.h>

// ---------------------------------------------------------------------------
// Stacked RNNCell+LN (H=2350,E=768) + single-head MHA + collapsed 2nd scan.
//   * scan2 collapses to one step at t_b=seq_len-1 (inputs are precomputed)
//   * MHA needs only 1 query row/batch: fold Wk/Wv through -> no K/V GEMMs
//   * scan1: persistent kernel, 1 grid barrier/step, LN folded into GEMMs
//     via state = (tau raw tanh f16, sum, sumsq): h.W = r*(tau.Wg) - mu*r*E + D
//   * f16 MFMA 16x16x32, fp32 accum (f16 state: 8x less noise than bf16)
//   * workspace ~226 MB with region reuse; if ws too small -> logits=7.0f
//     signature (diagnostic), never OOB.
// ---------------------------------------------------------------------------

#define HH 2350
#define EE 768
#define OO 19
#define BB 64
#define NT 256
#define HP 2368   // HH padded to mult of 64
#define EP 768
#define EPS 1e-5f

#define NZ1 74            // z1 blocks: 32 cols each -> 2368
#define NZ2 48            // z2 blocks: 16 cols each -> 768
#define NBLK (NZ1 + NZ2)  // 122 blocks, co-resident on 256 CUs (8 waves/blk)

typedef _Float16 f16;
typedef _Float16 f16x8 __attribute__((ext_vector_type(8)));
typedef float f32x4 __attribute__((ext_vector_type(4)));

__device__ inline f32x4 mfma16(f16x8 a, f16x8 b, f32x4 c) {
  return __builtin_amdgcn_mfma_f32_16x16x32_f16(a, b, c, 0, 0, 0);
}

__device__ inline float block_reduce_sum(float v, float* red4) {
  __syncthreads();
  for (int m = 32; m >= 1; m >>= 1) v += __shfl_down(v, m, 64);
  int lane = threadIdx.x & 63, wid = threadIdx.x >> 6;
  if (lane == 0) red4[wid] = v;
  __syncthreads();
  return red4[0] + red4[1] + red4[2] + red4[3];
}
__device__ inline float block_reduce_max(float v, float* red4) {
  __syncthreads();
  for (int m = 32; m >= 1; m >>= 1) v = fmaxf(v, __shfl_down(v, m, 64));
  int lane = threadIdx.x & 63, wid = threadIdx.x >> 6;
  if (lane == 0) red4[wid] = v;
  __syncthreads();
  return fmaxf(fmaxf(red4[0], red4[1]), fmaxf(red4[2], red4[3]));
}

// ---------------- setup kernels -------------------------------------------

__global__ __launch_bounds__(256) void k_sig(float* out, int n) {
  int i = blockIdx.x * 256 + threadIdx.x;
  if (i < n) out[i] = 7.0f;   // "workspace too small" signature
}

// LN over E of x, rows ordered (t*BB+b), output f16
__global__ __launch_bounds__(256) void k_ln_x(const float* __restrict__ x,
    const float* __restrict__ g, const float* __restrict__ be,
    f16* __restrict__ xn) {
  __shared__ float red4[4];
  int row = blockIdx.x;            // row = t*BB + b
  int t = row >> 6, b = row & 63;
  const float* xr = x + ((size_t)b * NT + t) * EE;
  float vals[3]; float p = 0.f, p2 = 0.f;
  #pragma unroll
  for (int i = 0; i < 3; ++i) {
    int k = threadIdx.x + 256 * i;
    vals[i] = xr[k]; p += vals[i]; p2 += vals[i] * vals[i];
  }
  float s = block_reduce_sum(p, red4);
  float s2 = block_reduce_sum(p2, red4);
  float mu = s * (1.f / EE);
  float r = rsqrtf(fmaxf(s2 * (1.f / EE) - mu * mu, 0.f) + EPS);
  #pragma unroll
  for (int i = 0; i < 3; ++i) {
    int k = threadIdx.x + 256 * i;
    xn[(size_t)row * EE + k] = (f16)((vals[i] - mu) * r * g[k] + be[k]);
  }
}

// cast f32 weight [rows][cols] -> f16 [rowsPad][ldd], optional per-col scale
__global__ __launch_bounds__(256) void k_cast(f16* __restrict__ dst,
    const float* __restrict__ src, int rows, int cols, int ldd,
    const float* __restrict__ scale) {
  int r = blockIdx.x;
  for (int c = threadIdx.x; c < ldd; c += 256) {
    float v = 0.f;
    if (r < rows && c < cols) {
      v = src[(size_t)r * cols + c];
      if (scale) v *= scale[c];
    }
    dst[(size_t)r * ldd + c] = (f16)v;
  }
}

// transposed cast: dst[j][n] = src[n][j]
__global__ __launch_bounds__(256) void k_castT(f16* __restrict__ dst,
    const float* __restrict__ src, int srcRows, int srcCols, int ldd) {
  __shared__ float tile[32][33];
  int jb = blockIdx.x * 32;  // dst row block (= src col)
  int nb = blockIdx.y * 32;  // dst col block (= src row)
  int tx = threadIdx.x & 31, ty = threadIdx.x >> 5;
  for (int i = ty; i < 32; i += 8) {
    int sr = nb + i, sc = jb + tx;
    tile[i][tx] = (sr < srcRows && sc < srcCols) ? src[(size_t)sr * srcCols + sc] : 0.f;
  }
  __syncthreads();
  for (int i = ty; i < 32; i += 8) {
    dst[(size_t)(jb + i) * ldd + (nb + tx)] = (f16)tile[tx][i];
  }
}

// E[r] = sum_k src[r][k]*g[k];  D[r] = sum_k src[r][k]*be[k]
__global__ __launch_bounds__(256) void k_rowdot(const float* __restrict__ src,
    const float* __restrict__ g, const float* __restrict__ be,
    int rows, int cols, float* __restrict__ Ev, float* __restrict__ Dv) {
  __shared__ float red4[4];
  int r = blockIdx.x;
  float pe = 0.f, pd = 0.f;
  if (r < rows) {
    for (int k = threadIdx.x; k < cols; k += 256) {
      float w = src[(size_t)r * cols + k];
      pe += w * g[k]; pd += w * be[k];
    }
  }
  float e = block_reduce_sum(pe, red4);
  float d = block_reduce_sum(pd, red4);
  if (threadIdx.x == 0) { Ev[r] = (r < rows) ? e : 0.f; Dv[r] = (r < rows) ? d : 0.f; }
}

__global__ __launch_bounds__(256) void k_addvec(const float* a, const float* b,
    int N, int NP, float* outv) {
  int i = blockIdx.x * 256 + threadIdx.x;
  if (i < NP) outv[i] = (i < N) ? a[i] + b[i] : 0.f;
}

// ---------------- generic f16 MFMA GEMM -----------------------------------
// C[M][N] = A[M][K] * Bw[N][K]^T (+bias) (+C if acc). 256 thr, 64x64 tile
__global__ __launch_bounds__(256) void k_gemm(const f16* __restrict__ A, int lda,
    const f16* __restrict__ Bw, int ldb, float* __restrict__ C, int ldc,
    int Nvalid, int K, const float* __restrict__ bias, int accFlag) {
  int tid = threadIdx.x, w = tid >> 6, lid = tid & 63;
  int l15 = lid & 15, lhi = lid >> 4;
  int m0 = blockIdx.y * 64 + 16 * w;
  int n0 = blockIdx.x * 64;
  const f16* Ap = A + ((size_t)(m0 + l15)) * lda + lhi * 8;
  const f16* Bp = Bw + ((size_t)(n0 + l15)) * ldb + lhi * 8;
  f32x4 acc[4];
  #pragma unroll
  for (int j = 0; j < 4; ++j) acc[j] = (f32x4){0.f, 0.f, 0.f, 0.f};
  for (int k = 0; k < K; k += 32) {
    f16x8 a = *(const f16x8*)(Ap + k);
    #pragma unroll
    for (int j = 0; j < 4; ++j) {
      f16x8 b = *(const f16x8*)(Bp + (size_t)16 * j * ldb + k);
      acc[j] = mfma16(a, b, acc[j]);
    }
  }
  #pragma unroll
  for (int j = 0; j < 4; ++j) {
    int col = n0 + 16 * j + l15;
    #pragma unroll
    for (int q = 0; q < 4; ++q) {
      int row = m0 + lhi * 4 + q;
      float v = acc[j][q];
      if (bias && col < Nvalid) v += bias[col];
      size_t ci = (size_t)row * ldc + col;
      if (accFlag) v += C[ci];
      C[ci] = v;
    }
  }
}

// same but f16 output (big XW1 precompute; no acc)
__global__ __launch_bounds__(256) void k_gemm_h(const f16* __restrict__ A, int lda,
    const f16* __restrict__ Bw, int ldb, f16* __restrict__ C, int ldc,
    int Nvalid, int K, const float* __restrict__ bias) {
  int tid = threadIdx.x, w = tid >> 6, lid = tid & 63;
  int l15 = lid & 15, lhi = lid >> 4;
  int m0 = blockIdx.y * 64 + 16 * w;
  int n0 = blockIdx.x * 64;
  const f16* Ap = A + ((size_t)(m0 + l15)) * lda + lhi * 8;
  const f16* Bp = Bw + ((size_t)(n0 + l15)) * ldb + lhi * 8;
  f32x4 acc[4];
  #pragma unroll
  for (int j = 0; j < 4; ++j) acc[j] = (f32x4){0.f, 0.f, 0.f, 0.f};
  for (int k = 0; k < K; k += 32) {
    f16x8 a = *(const f16x8*)(Ap + k);
    #pragma unroll
    for (int j = 0; j < 4; ++j) {
      f16x8 b = *(const f16x8*)(Bp + (size_t)16 * j * ldb + k);
      acc[j] = mfma16(a, b, acc[j]);
    }
  }
  #pragma unroll
  for (int j = 0; j < 4; ++j) {
    int col = n0 + 16 * j + l15;
    #pragma unroll
    for (int q = 0; q < 4; ++q) {
      int row = m0 + lhi * 4 + q;
      float v = acc[j][q];
      if (bias && col < Nvalid) v += bias[col];
      C[(size_t)row * ldc + col] = (f16)v;
    }
  }
}

// ---------------- persistent scan kernel ----------------------------------

__device__ inline void gridbar(unsigned int* bar) {
  __syncthreads();
  if (threadIdx.x == 0) {
    __threadfence();
    unsigned int g = __hip_atomic_load(bar + 1, __ATOMIC_RELAXED, __HIP_MEMORY_SCOPE_AGENT);
    unsigned int c = __hip_atomic_fetch_add(bar, 1u, __ATOMIC_ACQ_REL, __HIP_MEMORY_SCOPE_AGENT);
    if (c == (unsigned int)(NBLK - 1)) {
      __hip_atomic_store(bar, 0u, __ATOMIC_RELAXED, __HIP_MEMORY_SCOPE_AGENT);
      __hip_atomic_fetch_add(bar + 1, 1u, __ATOMIC_RELEASE, __HIP_MEMORY_SCOPE_AGENT);
    } else {
      while (__hip_atomic_load(bar + 1, __ATOMIC_ACQUIRE, __HIP_MEMORY_SCOPE_AGENT) == g)
        __builtin_amdgcn_s_sleep(2);
    }
    __threadfence();
  }
  __syncthreads();
}

__global__ __launch_bounds__(512, 1) void k_scan(
    const f16* __restrict__ XW1,
    const f16* __restrict__ W1g, const float* __restrict__ E1v, const float* __restrict__ D1v,
    const f16* __restrict__ W2g, const float* __restrict__ E2v, const float* __restrict__ D2v,
    const f16* __restrict__ Whg, const float* __restrict__ Ehv, const float* __restrict__ Dhv,
    const float* __restrict__ bih2, const float* __restrict__ bhh2,
    f16* __restrict__ hist1, f16* __restrict__ hist2,
    float* __restrict__ stats1, float* __restrict__ stats2,
    const int* __restrict__ sl, unsigned int* __restrict__ bar) {
  const int blk = blockIdx.x;
  const int tid = threadIdx.x;
  const int w = tid >> 6;
  const int lid = tid & 63;
  const int l15 = lid & 15;
  const int lhi = lid >> 4;
  __shared__ float partB[4][16][17];
  const bool isZ1 = (blk < NZ1);

  for (int t = 0; t <= NT; ++t) {
    if (isZ1) {
      if (t < NT) {
        // ---- cell 1, step t:  z1 = r*(tau1.W1g) - mu*r*E1 + D1 + XW1[t]
        const int n0 = blk * 32 + 16 * (w >> 2);
        const int m0 = 16 * (w & 3);
        const int col = n0 + l15;
        f32x4 acc0 = {0.f, 0.f, 0.f, 0.f}, acc1 = {0.f, 0.f, 0.f, 0.f};
        if (t > 0) {
          const f16* Ap = hist1 + ((size_t)(t - 1) * BB + m0 + l15) * HP + lhi * 8;
          const f16* Bp = W1g + (size_t)col * HP + lhi * 8;
          for (int k = 0; k < HP; k += 64) {
            f16x8 a0 = *(const f16x8*)(Ap + k);
            f16x8 b0 = *(const f16x8*)(Bp + k);
            f16x8 a1 = *(const f16x8*)(Ap + k + 32);
            f16x8 b1 = *(const f16x8*)(Bp + k + 32);
            acc0 = mfma16(a0, b0, acc0);
            acc1 = mfma16(a1, b1, acc1);
          }
        }
        float sv[4], qv[4]; int bq_[4]; bool act_[4];
        #pragma unroll
        for (int q = 0; q < 4; ++q) {
          int b = m0 + lhi * 4 + q;
          int slb = sl[b];
          bool active = (t < slb);
          size_t xi = ((size_t)t * BB + b) * HP + col;
          float v;
          if (t == 0) {
            v = (float)XW1[xi];     // h1 starts at 0: no state term, no D1
          } else {
            float accq = acc0[q] + acc1[q];
            int ts = min(t - 1, slb - 1);
            float s1 = stats1[((size_t)ts * BB + b) * 2 + 0];
            float s2 = stats1[((size_t)ts * BB + b) * 2 + 1];
            float mu = s1 * (1.f / HH);
            float r = rsqrtf(fmaxf(s2 * (1.f / HH) - mu * mu, 0.f) + EPS);
            v = r * accq - mu * r * E1v[col] + D1v[col] + (float)XW1[xi];
          }
          float tau = tanhf(v);
          if (col >= HH) tau = 0.f;   // pad cols stay 0
          f16 st;
          if (active) st = (f16)tau;
          else        st = hist1[((size_t)(t - 1) * BB + b) * HP + col];
          hist1[((size_t)t * BB + b) * HP + col] = st;
          float tq = active ? (float)st : 0.f;
          sv[q] = tq; qv[q] = tq * tq; bq_[q] = b; act_[q] = active;
        }
        #pragma unroll
        for (int m = 1; m <= 8; m <<= 1) {
          #pragma unroll
          for (int q = 0; q < 4; ++q) {
            sv[q] += __shfl_xor(sv[q], m, 64);
            qv[q] += __shfl_xor(qv[q], m, 64);
          }
        }
        if (l15 == 0) {
          #pragma unroll
          for (int q = 0; q < 4; ++q) if (act_[q]) {
            atomicAdd(&stats1[((size_t)t * BB + bq_[q]) * 2 + 0], sv[q]);
            atomicAdd(&stats1[((size_t)t * BB + bq_[q]) * 2 + 1], qv[q]);
          }
        }
      }
    } else {
      if (t >= 1) {
        // ---- cell 2, step s=t-1 (one step behind; fresh h1n == hist1[s])
        const int s = t - 1;
        const int n0 = (blk - NZ1) * 16;
        const int col = n0 + l15;
        f32x4 accA0 = {0.f, 0.f, 0.f, 0.f}, accA1 = {0.f, 0.f, 0.f, 0.f};
        if (w >= 4) {
          const int m0 = 16 * (w - 4);
          f32x4 aB0 = {0.f, 0.f, 0.f, 0.f}, aB1 = {0.f, 0.f, 0.f, 0.f};
          if (s >= 1) {
            const f16* Ap = hist2 + ((size_t)(s - 1) * BB + m0 + l15) * EP + lhi * 8;
            const f16* Bp = Whg + (size_t)col * EP + lhi * 8;
            for (int k = 0; k < EP; k += 64) {
              f16x8 a0 = *(const f16x8*)(Ap + k);
              f16x8 b0 = *(const f16x8*)(Bp + k);
              f16x8 a1 = *(const f16x8*)(Ap + k + 32);
              f16x8 b1 = *(const f16x8*)(Bp + k + 32);
              aB0 = mfma16(a0, b0, aB0);
              aB1 = mfma16(a1, b1, aB1);
            }
          }
          #pragma unroll
          for (int q = 0; q < 4; ++q) partB[w - 4][lhi * 4 + q][l15] = aB0[q] + aB1[q];
        } else {
          const int m0 = 16 * w;
          const f16* Ap = hist1 + ((size_t)s * BB + m0 + l15) * HP + lhi * 8;
          const f16* Bp = W2g + (size_t)col * HP + lhi * 8;
          for (int k = 0; k < HP; k += 64) {
            f16x8 a0 = *(const f16x8*)(Ap + k);
            f16x8 b0 = *(const f16x8*)(Bp + k);
            f16x8 a1 = *(const f16x8*)(Ap + k + 32);
            f16x8 b1 = *(const f16x8*)(Bp + k + 32);
            accA0 = mfma16(a0, b0, accA0);
            accA1 = mfma16(a1, b1, accA1);
          }
        }
        __syncthreads();
        if (w < 4) {
          const int m0 = 16 * w;
          float sv[4], qv[4]; int bq_[4]; bool act_[4];
          #pragma unroll
          for (int q = 0; q < 4; ++q) {
            int b = m0 + lhi * 4 + q;
            int slb = sl[b];
            bool active = (s < slb);
            float accA = accA0[q] + accA1[q];
            float s1 = stats1[((size_t)s * BB + b) * 2 + 0];
            float s2 = stats1[((size_t)s * BB + b) * 2 + 1];
            float mu1 = s1 * (1.f / HH);
            float r1 = rsqrtf(fmaxf(s2 * (1.f / HH) - mu1 * mu1, 0.f) + EPS);
            float v = r1 * accA - mu1 * r1 * E2v[col] + D2v[col] + bih2[col] + bhh2[col];
            if (s >= 1) {
              float accB = partB[w][lhi * 4 + q][l15];
              int t2 = min(s - 1, slb - 1);
              float u1s = stats2[((size_t)t2 * BB + b) * 2 + 0];
              float u2s = stats2[((size_t)t2 * BB + b) * 2 + 1];
              float mu2 = u1s * (1.f / EE);
              float r2 = rsqrtf(fmaxf(u2s * (1.f / EE) - mu2 * mu2, 0.f) + EPS);
              v += r2 * accB - mu2 * r2 * Ehv[col] + Dhv[col];
            }
            float tau = tanhf(v);
            f16 st;
            if (active) st = (f16)tau;
            else        st = hist2[((size_t)(s - 1) * BB + b) * EP + col];
            hist2[((size_t)s * BB + b) * EP + col] = st;
            float tq = active ? (float)st : 0.f;
            sv[q] = tq; qv[q] = tq * tq; bq_[q] = b; act_[q] = active;
          }
          #pragma unroll
          for (int m = 1; m <= 8; m <<= 1) {
            #pragma unroll
            for (int q = 0; q < 4; ++q) {
              sv[q] += __shfl_xor(sv[q], m, 64);
              qv[q] += __shfl_xor(qv[q], m, 64);
            }
          }
          if (l15 == 0) {
            #pragma unroll
            for (int q = 0; q < 4; ++q) if (act_[q]) {
              atomicAdd(&stats2[((size_t)s * BB + bq_[q]) * 2 + 0], sv[q]);
              atomicAdd(&stats2[((size_t)s * BB + bq_[q]) * 2 + 1], qv[q]);
            }
          }
        }
      }
    }
    gridbar(bar);
  }
}

// ---------------- post-scan kernels ---------------------------------------

// sections: 0 -> hq1 (h1s[t_b] f16), 1 -> hq2, 2 -> u1 = XW1[t_b] copy (f32)
__global__ __launch_bounds__(256) void k_gather(
    const f16* __restrict__ hist1, const float* __restrict__ stats1,
    const f16* __restrict__ hist2, const float* __restrict__ stats2,
    const f16* __restrict__ XW1, const int* __restrict__ sl,
    const float* __restrict__ g1, const float* __restrict__ be1,
    const float* __restrict__ g2, const float* __restrict__ be2,
    f16* __restrict__ hq1, f16* __restrict__ hq2, float* __restrict__ u1) {
  int sec = blockIdx.x >> 6, b = blockIdx.x & 63;
  int tb = sl[b] - 1;
  if (sec == 0) {
    float s1 = stats1[((size_t)tb * BB + b) * 2 + 0];
    float s2 = stats1[((size_t)tb * BB + b) * 2 + 1];
    float mu = s1 * (1.f / HH);
    float r = rsqrtf(fmaxf(s2 * (1.f / HH) - mu * mu, 0.f) + EPS);
    for (int k = threadIdx.x; k < HP; k += 256) {
      float h = 0.f;
      if (k < HH) h = ((float)hist1[((size_t)tb * BB + b) * HP + k] - mu) * r * g1[k] + be1[k];
      hq1[(size_t)b * HP + k] = (f16)h;
    }
  } else if (sec == 1) {
    float s1 = stats2[((size_t)tb * BB + b) * 2 + 0];
    float s2 = stats2[((size_t)tb * BB + b) * 2 + 1];
    float mu = s1 * (1.f / EE);
    float r = rsqrtf(fmaxf(s2 * (1.f / EE) - mu * mu, 0.f) + EPS);
    for (int k = threadIdx.x; k < EP; k += 256) {
      float h = ((float)hist2[((size_t)tb * BB + b) * EP + k] - mu) * r * g2[k] + be2[k];
      hq2[(size_t)b * EP + k] = (f16)h;
    }
  } else {
    for (int n = threadIdx.x; n < HP; n += 256)
      u1[(size_t)b * HP + n] = (float)XW1[((size_t)tb * BB + b) * HP + n];
  }
}

__global__ __launch_bounds__(256) void k_cast64(const float* __restrict__ src,
    f16* __restrict__ dst, int N, int ld) {
  int b = blockIdx.x;
  for (int k = threadIdx.x; k < ld; k += 256)
    dst[(size_t)b * ld + k] = (f16)((k < N) ? src[(size_t)b * ld + k] : 0.f);
}

__global__ __launch_bounds__(256) void k_qg(const float* __restrict__ qk, int ld,
    const float* __restrict__ g, int N, float* __restrict__ qg, float* __restrict__ S0) {
  __shared__ float red4[4];
  int b = blockIdx.x;
  float p = 0.f;
  for (int k = threadIdx.x; k < ld; k += 256) {
    float v = (k < N) ? qk[(size_t)b * ld + k] * g[k] : 0.f;
    qg[(size_t)b * ld + k] = v;
    p += v;
  }
  float s = block_reduce_sum(p, red4);
  if (threadIdx.x == 0) S0[b] = s;
}

__global__ __launch_bounds__(256) void k_scores(const float* __restrict__ qg, int ldq,
    const f16* __restrict__ hist, int ldh, const float* __restrict__ stats,
    const float* __restrict__ S0, const int* __restrict__ sl, int N, float invsqd,
    float* __restrict__ scores) {
  __shared__ float red4[4];
  int s = blockIdx.x, b = blockIdx.y;
  const float* qrow = qg + (size_t)b * ldq;
  const f16* hrow = hist + ((size_t)s * BB + b) * ldh;
  float p = 0.f;
  for (int k = threadIdx.x; k < N; k += 256) p += qrow[k] * (float)hrow[k];
  float dot = block_reduce_sum(p, red4);
  if (threadIdx.x == 0) {
    int ss = min(s, sl[b] - 1);
    float s1 = stats[((size_t)ss * BB + b) * 2 + 0];
    float s2 = stats[((size_t)ss * BB + b) * 2 + 1];
    float mu = s1 / N;
    float r = rsqrtf(fmaxf(s2 / N - mu * mu, 0.f) + EPS);
    scores[(size_t)b * NT + s] = (r * dot - r * mu * S0[b]) * invsqd;
  }
}

__global__ __launch_bounds__(256) void k_softmax(const float* __restrict__ scores,
    const float* __restrict__ stats, const int* __restrict__ sl, int N,
    float* __restrict__ aw, float* __restrict__ cb) {
  __shared__ float red4[4];
  int b = blockIdx.x, s = threadIdx.x;
  float sc = scores[(size_t)b * NT + s];
  float m = block_reduce_max(sc, red4);
  float e = expf(sc - m);
  float Z = block_reduce_sum(e, red4);
  float a = e / Z;
  int ss = min(s, sl[b] - 1);
  float s1 = stats[((size_t)ss * BB + b) * 2 + 0];
  float s2 = stats[((size_t)ss * BB + b) * 2 + 1];
  float mu = s1 / N;
  float r = rsqrtf(fmaxf(s2 / N - mu * mu, 0.f) + EPS);
  aw[(size_t)b * NT + s] = a * r;
  float c = block_reduce_sum(a * r * mu, red4);
  if (threadIdx.x == 0) cb[b] = c;
}

__global__ __launch_bounds__(256) void k_wsum(const f16* __restrict__ hist, int ldh,
    const float* __restrict__ aw, const float* __restrict__ cb,
    const float* __restrict__ g, const float* __restrict__ be, int N,
    f16* __restrict__ out, int ldo) {
  __shared__ float awS[NT];
  int b = blockIdx.y;
  int k = blockIdx.x * 256 + threadIdx.x;
  awS[threadIdx.x] = aw[(size_t)b * NT + threadIdx.x];
  __syncthreads();
  if (k >= ldo) return;
  float acc = 0.f;
  const f16* hb = hist + (size_t)b * ldh + k;
  for (int s = 0; s < NT; ++s) acc += awS[s] * (float)hb[(size_t)s * BB * ldh];
  float o = (k < N) ? g[k] * (acc - cb[b]) + be[k] : 0.f;
  out[(size_t)b * ldo + k] = (f16)o;
}

// out = LN(tanh(u)) row-wise, f16 (outH) or f32 (outF)
__global__ __launch_bounds__(256) void k_lnrow(const float* __restrict__ u, int ldu,
    int N, const float* __restrict__ g, const float* __restrict__ be,
    f16* __restrict__ outH, float* __restrict__ outF, int ldo) {
  __shared__ float tl[HP];
  __shared__ float red4[4];
  int b = blockIdx.x;
  float p = 0.f, p2 = 0.f;
  for (int k = threadIdx.x; k < N; k += 256) {
    float tau = tanhf(u[(size_t)b * ldu + k]);
    tl[k] = tau; p += tau; p2 += tau * tau;
  }
  float s = block_reduce_sum(p, red4);
  float s2 = block_reduce_sum(p2, red4);
  float mu = s / N;
  float r = rsqrtf(fmaxf(s2 / N - mu * mu, 0.f) + EPS);
  __syncthreads();
  for (int k = threadIdx.x; k < ldo; k += 256) {
    float h = (k < N) ? (tl[k] - mu) * r * g[k] + be[k] : 0.f;
    if (outH) outH[(size_t)b * ldo + k] = (f16)h;
    else outF[(size_t)b * ldo + k] = h;
  }
}

__global__ __launch_bounds__(256) void k_logits(const float* __restrict__ h2,
    const float* __restrict__ Wc, const float* __restrict__ bc, float* __restrict__ out) {
  __shared__ float hrow[EP];
  __shared__ float red4[4];
  int b = blockIdx.x;
  for (int k = threadIdx.x; k < EP; k += 256) hrow[k] = h2[(size_t)b * EP + k];
  __syncthreads();
  for (int o = 0; o < OO; ++o) {
    float p = 0.f;
    for (int k = threadIdx.x; k < EP; k += 256) p += hrow[k] * Wc[(size_t)o * EP + k];
    float v = block_reduce_sum(p, red4);
    if (threadIdx.x == 0) {
      v += bc[o];
      out[(size_t)b * OO + o] = fminf(fmaxf(v, -10.f), 10.f);
    }
  }
}

// ---------------------------------------------------------------------------

extern "C" void kernel_launch(void* const* d_in, const int* in_sizes, int n_in,
                              void* d_out, int out_size, void* d_ws, size_t ws_size,
                              hipStream_t stream) {
  const float* x     = (const float*)d_in[0];
  const int*   sl    = (const int*)d_in[1];
  const float* in_g  = (const float*)d_in[2];
  const float* in_b  = (const float*)d_in[3];
  const float* Wih1  = (const float*)d_in[4];
  const float* bih1  = (const float*)d_in[5];
  const float* Whh1  = (const float*)d_in[6];
  const float* bhh1  = (const float*)d_in[7];
  const float* g1    = (const float*)d_in[8];
  const float* be1   = (const float*)d_in[9];
  const float* Wih2  = (const float*)d_in[10];
  const float* bih2  = (const float*)d_in[11];
  const float* Whh2  = (const float*)d_in[12];
  const float* bhh2  = (const float*)d_in[13];
  const float* g2    = (const float*)d_in[14];
  const float* be2   = (const float*)d_in[15];
  const float* Wqkv1 = (const float*)d_in[16];
  const float* bqkv1 = (const float*)d_in[17];
  const float* Wo1w  = (const float*)d_in[18];
  const float* bo1   = (const float*)d_in[19];
  const float* Wqkv2 = (const float*)d_in[20];
  const float* bqkv2 = (const float*)d_in[21];
  const float* Wo2w  = (const float*)d_in[22];
  const float* bo2   = (const float*)d_in[23];
  const float* Wc    = (const float*)d_in[24];
  const float* bc    = (const float*)d_in[25];
  float* outp = (float*)d_out;

  char* base = (char*)d_ws;
  size_t off = 0;
  auto alloc = [&](size_t bytes) -> void* {
    void* p = base + off;
    off = (off + bytes + 255) & ~(size_t)255;
    return p;
  };
  // --- persistent (scan-lifetime) buffers ---
  float* stats1 = (float*)alloc((size_t)NT * BB * 2 * 4);
  float* stats2 = (float*)alloc((size_t)NT * BB * 2 * 4);
  unsigned int* bar = (unsigned int*)alloc(256);
  f16* XW1h  = (f16*)alloc((size_t)NT * BB * HP * 2);   // 77.6 MB
  f16* hist1 = (f16*)alloc((size_t)NT * BB * HP * 2);   // 77.6 MB
  f16* hist2 = (f16*)alloc((size_t)NT * BB * EP * 2);   // 25.2 MB
  f16* W1g   = (f16*)alloc((size_t)HP * HP * 2);        // 11.2 MB (reused post-scan)
  f16* W2g   = (f16*)alloc((size_t)EP * HP * 2);        //  3.6 MB (reused post-scan)
  f16* Whg   = (f16*)alloc((size_t)EP * EP * 2);        //  1.2 MB
  float* E1v = (float*)alloc(HP * 4);
  float* D1v = (float*)alloc(HP * 4);
  float* E2v = (float*)alloc(EP * 4);
  float* D2v = (float*)alloc(EP * 4);
  float* Ehv = (float*)alloc(EP * 4);
  float* Dhv = (float*)alloc(EP * 4);
  float* bsum1 = (float*)alloc(HP * 4);

  // --- reuse region R: pre-scan {xnh, Wih1h}; post-scan activation smalls ---
  char* R = (char*)alloc((size_t)29 * 1024 * 1024);
  f16* xnh   = (f16*)R;                                  // 25,165,824 B
  f16* Wih1h = (f16*)(R + 25165824);                     //  3,637,248 B
  size_t ro = 0;
  auto ralloc = [&](size_t bytes) -> void* {
    void* p = R + ro;
    ro = (ro + bytes + 255) & ~(size_t)255;
    return p;
  };
  f16* hq1in = (f16*)ralloc((size_t)BB * HP * 2);
  f16* hq2in = (f16*)ralloc((size_t)BB * EP * 2);
  float* q1   = (float*)ralloc((size_t)BB * HP * 4);
  f16* q1h    = (f16*)ralloc((size_t)BB * HP * 2);
  float* qk1  = (float*)ralloc((size_t)BB * HP * 4);
  float* qg1  = (float*)ralloc((size_t)BB * HP * 4);
  float* S01  = (float*)ralloc(BB * 4);
  float* scores1 = (float*)ralloc((size_t)BB * NT * 4);
  float* aw1 = (float*)ralloc((size_t)BB * NT * 4);
  float* c1v = (float*)ralloc(BB * 4);
  f16* wsum1h = (f16*)ralloc((size_t)BB * HP * 2);
  float* out1 = (float*)ralloc((size_t)BB * HP * 4);
  f16* out1h = (f16*)ralloc((size_t)BB * HP * 2);
  float* mha1 = (float*)ralloc((size_t)BB * HP * 4);
  f16* mha1h = (f16*)ralloc((size_t)BB * HP * 2);
  float* q2   = (float*)ralloc((size_t)BB * EP * 4);
  f16* q2h    = (f16*)ralloc((size_t)BB * EP * 2);
  float* qk2  = (float*)ralloc((size_t)BB * EP * 4);
  float* qg2  = (float*)ralloc((size_t)BB * EP * 4);
  float* S02  = (float*)ralloc(BB * 4);
  float* scores2 = (float*)ralloc((size_t)BB * NT * 4);
  float* aw2 = (float*)ralloc((size_t)BB * NT * 4);
  float* c2v = (float*)ralloc(BB * 4);
  f16* wsum2h = (f16*)ralloc((size_t)BB * EP * 2);
  float* out2 = (float*)ralloc((size_t)BB * EP * 4);
  f16* out2h = (f16*)ralloc((size_t)BB * EP * 2);
  float* mha2 = (float*)ralloc((size_t)BB * EP * 4);
  f16* mha2h = (f16*)ralloc((size_t)BB * EP * 2);
  float* u1 = (float*)ralloc((size_t)BB * HP * 4);
  f16* h1nh = (f16*)ralloc((size_t)BB * HP * 2);
  float* u2 = (float*)ralloc((size_t)BB * EP * 4);
  float* h2nf = (float*)ralloc((size_t)BB * EP * 4);
  // (ro stays < 9 MB < 29 MB region; pre/post lifetimes are stream-ordered)

  // post-scan weight aliases (sequential use, cast-before-each-GEMM):
  f16* Wbig = W1g;   // holds Wq1 -> WkT1 -> Wv1 -> Wo1 -> Whh1 in turn
  f16* Wsm  = W2g;   // holds Wq2 -> WkT2 -> Wv2 -> Wo2 -> Whh2 -> Wih2 in turn

  if (off > ws_size) {  // workspace too small: emit diagnostic signature
    k_sig<<<(out_size + 255) / 256, 256, 0, stream>>>(outp, out_size);
    return;
  }

  hipMemsetAsync(stats1, 0, (size_t)NT * BB * 2 * 4, stream);
  hipMemsetAsync(stats2, 0, (size_t)NT * BB * 2 * 4, stream);
  hipMemsetAsync(bar, 0, 256, stream);

  // input LN -> f16
  k_ln_x<<<NT * BB, 256, 0, stream>>>(x, in_g, in_b, xnh);

  // scan-phase weights
  k_cast<<<HP, 256, 0, stream>>>(W1g, Whh1, HH, HH, HP, g1);
  k_cast<<<HP, 256, 0, stream>>>(Wih1h, Wih1, HH, EE, EE, nullptr);
  k_cast<<<EP, 256, 0, stream>>>(W2g, Wih2, EE, HH, HP, g1);
  k_cast<<<EP, 256, 0, stream>>>(Whg, Whh2, EE, EE, EP, g2);

  // folded-LN constant vectors
  k_rowdot<<<HP, 256, 0, stream>>>(Whh1, g1, be1, HH, HH, E1v, D1v);
  k_rowdot<<<EP, 256, 0, stream>>>(Wih2, g1, be1, EE, HH, E2v, D2v);
  k_rowdot<<<EP, 256, 0, stream>>>(Whh2, g2, be2, EE, EE, Ehv, Dhv);
  k_addvec<<<(HP + 255) / 256, 256, 0, stream>>>(bih1, bhh1, HH, HP, bsum1);

  // XW1[t,b,:] = LN(x)@Wih1^T + bih1 + bhh1  (f16; shared by both scans)
  k_gemm_h<<<dim3(HP / 64, (NT * BB) / 64), 256, 0, stream>>>(
      xnh, EE, Wih1h, EE, XW1h, HP, HH, EE, bsum1);

  // persistent scan (257 barrier-separated iterations)
  k_scan<<<NBLK, 512, 0, stream>>>(XW1h, W1g, E1v, D1v, W2g, E2v, D2v, Whg, Ehv, Dhv,
                                   bih2, bhh2, hist1, hist2, stats1, stats2, sl, bar);

  // gather per-batch rows at t_b = sl-1 (also frees R for post-scan smalls)
  k_gather<<<192, 256, 0, stream>>>(hist1, stats1, hist2, stats2, XW1h, sl,
                                    g1, be1, g2, be2, hq1in, hq2in, u1);

  const float invsq1 = 1.f / sqrtf((float)HH);
  const float invsq2 = 1.f / sqrtf((float)EE);

  // ---- MHA1 (collapsed; q.bk and qk.be1 constants drop out of softmax) ----
  k_cast<<<HP, 256, 0, stream>>>(Wbig, Wqkv1, HH, HH, HP, nullptr);              // Wq1
  k_gemm<<<dim3(37, 1), 256, 0, stream>>>(hq1in, HP, Wbig, HP, q1, HP, HH, HP, bqkv1, 0);
  k_cast64<<<BB, 256, 0, stream>>>(q1, q1h, HH, HP);
  k_castT<<<dim3(HP / 32, HP / 32), 256, 0, stream>>>(Wbig, Wqkv1 + (size_t)HH * HH, HH, HH, HP); // Wk^T
  k_gemm<<<dim3(37, 1), 256, 0, stream>>>(q1h, HP, Wbig, HP, qk1, HP, HH, HP, nullptr, 0);
  k_qg<<<BB, 256, 0, stream>>>(qk1, HP, g1, HH, qg1, S01);
  k_scores<<<dim3(NT, BB), 256, 0, stream>>>(qg1, HP, hist1, HP, stats1, S01, sl, HH, invsq1, scores1);
  k_softmax<<<BB, 256, 0, stream>>>(scores1, stats1, sl, HH, aw1, c1v);
  k_wsum<<<dim3((HP + 255) / 256, BB), 256, 0, stream>>>(hist1, HP, aw1, c1v, g1, be1, HH, wsum1h, HP);
  k_cast<<<HP, 256, 0, stream>>>(Wbig, Wqkv1 + (size_t)2 * HH * HH, HH, HH, HP, nullptr); // Wv1
  k_gemm<<<dim3(37, 1), 256, 0, stream>>>(wsum1h, HP, Wbig, HP, out1, HP, HH, HP,
                                          bqkv1 + (size_t)2 * HH, 0);
  k_cast64<<<BB, 256, 0, stream>>>(out1, out1h, HH, HP);
  k_cast<<<HP, 256, 0, stream>>>(Wbig, Wo1w, HH, HH, HP, nullptr);               // Wo1
  k_gemm<<<dim3(37, 1), 256, 0, stream>>>(out1h, HP, Wbig, HP, mha1, HP, HH, HP, bo1, 0);
  k_cast64<<<BB, 256, 0, stream>>>(mha1, mha1h, HH, HP);

  // ---- MHA2 (collapsed) ----
  k_cast<<<EP, 256, 0, stream>>>(Wsm, Wqkv2, EE, EE, EP, nullptr);               // Wq2
  k_gemm<<<dim3(12, 1), 256, 0, stream>>>(hq2in, EP, Wsm, EP, q2, EP, EE, EP, bqkv2, 0);
  k_cast64<<<BB, 256, 0, stream>>>(q2, q2h, EE, EP);
  k_castT<<<dim3(EP / 32, EP / 32), 256, 0, stream>>>(Wsm, Wqkv2 + (size_t)EE * EE, EE, EE, EP); // Wk^T
  k_gemm<<<dim3(12, 1), 256, 0, stream>>>(q2h, EP, Wsm, EP, qk2, EP, EE, EP, nullptr, 0);
  k_qg<<<BB, 256, 0, stream>>>(qk2, EP, g2, EE, qg2, S02);
  k_scores<<<dim3(NT, BB), 256, 0, stream>>>(qg2, EP, hist2, EP, stats2, S02, sl, EE, invsq2, scores2);
  k_softmax<<<BB, 256, 0, stream>>>(scores2, stats2, sl, EE, aw2, c2v);
  k_wsum<<<dim3(EP / 256, BB), 256, 0, stream>>>(hist2, EP, aw2, c2v, g2, be2, EE, wsum2h, EP);
  k_cast<<<EP, 256, 0, stream>>>(Wsm, Wqkv2 + (size_t)2 * EE * EE, EE, EE, EP, nullptr); // Wv2
  k_gemm<<<dim3(12, 1), 256, 0, stream>>>(wsum2h, EP, Wsm, EP, out2, EP, EE, EP,
                                          bqkv2 + (size_t)2 * EE, 0);
  k_cast64<<<BB, 256, 0, stream>>>(out2, out2h, EE, EP);
  k_cast<<<EP, 256, 0, stream>>>(Wsm, Wo2w, EE, EE, EP, nullptr);                // Wo2
  k_gemm<<<dim3(12, 1), 256, 0, stream>>>(out2h, EP, Wsm, EP, mha2, EP, EE, EP, bo2, 0);
  k_cast64<<<BB, 256, 0, stream>>>(mha2, mha2h, EE, EP);

  // ---- collapsed scan-2 final step + classifier ----
  k_cast<<<HP, 256, 0, stream>>>(Wbig, Whh1, HH, HH, HP, nullptr);               // Whh1 raw
  k_gemm<<<dim3(37, 1), 256, 0, stream>>>(mha1h, HP, Wbig, HP, u1, HP, HH, HP, nullptr, 1);
  k_lnrow<<<BB, 256, 0, stream>>>(u1, HP, HH, g1, be1, h1nh, nullptr, HP);
  k_cast<<<EP, 256, 0, stream>>>(Wsm, Wih2, EE, HH, HP, nullptr);                // Wih2 raw
  k_gemm<<<dim3(12, 1), 256, 0, stream>>>(h1nh, HP, Wsm, HP, u2, EP, EE, HP, bih2, 0);
  k_cast<<<EP, 256, 0, stream>>>(Wsm, Whh2, EE, EE, EP, nullptr);                // Whh2 raw
  k_gemm<<<dim3(12, 1), 256, 0, stream>>>(mha2h, EP, Wsm, EP, u2, EP, EE, EP, bhh2, 1);
  k_lnrow<<<BB, 256, 0, stream>>>(u2, EP, EE, g2, be2, nullptr, h2nf, EP);
  k_logits<<<BB, 256, 0, stream>>>(h2nf, Wc, bc, outp);
}

// Round 6
// 10142.559 us; speedup vs baseline: 1.8979x; 1.8979x over previous
//
#include <hip/hip_runtime.h>

// ---------------------------------------------------------------------------
// Stacked RNNCell+LN (H=2350,E=768) + single-head MHA + collapsed 2nd scan.
//   * scan2 collapses to one step at t_b=seq_len-1; MHA folded (no K/V GEMMs)
//   * scan1: persistent kernel, 1 grid barrier/step, LN folded via
//     state = (tau f16, sum, sumsq): h.W = r*(tau.Wg) - mu*r*E + D
//   * THIS ROUND: weights LDS-resident (dodge per-barrier L2 invalidation),
//     depth-8 register-ring prefetch for the hist stream (hide LLC latency),
//     8-way-split stats atomics (kill same-line contention).
// ---------------------------------------------------------------------------

#define HH 2350
#define EE 768
#define OO 19
#define BB 64
#define NT 256
#define HP 2368   // HH padded to mult of 64
#define EP 768
#define EPS 1e-5f

#define NZ1 74            // z1 blocks: 32 cols each -> 2368
#define NZ2 48            // z2 blocks: 16 cols each -> 768
#define NBLK (NZ1 + NZ2)  // 122 blocks, co-resident (1/CU, LDS-limited)
#define BP 2376           // LDS row pitch (f16) for K=2368 (+8 pad)
#define WP 776            // LDS row pitch (f16) for K=768  (+8 pad)
#define NPART 8           // stats atomic split

typedef _Float16 f16;
typedef _Float16 f16x8 __attribute__((ext_vector_type(8)));
typedef float f32x4 __attribute__((ext_vector_type(4)));

__device__ inline f32x4 mfma16(f16x8 a, f16x8 b, f32x4 c) {
  return __builtin_amdgcn_mfma_f32_16x16x32_f16(a, b, c, 0, 0, 0);
}

__device__ inline float block_reduce_sum(float v, float* red4) {
  __syncthreads();
  for (int m = 32; m >= 1; m >>= 1) v += __shfl_down(v, m, 64);
  int lane = threadIdx.x & 63, wid = threadIdx.x >> 6;
  if (lane == 0) red4[wid] = v;
  __syncthreads();
  return red4[0] + red4[1] + red4[2] + red4[3];
}
__device__ inline float block_reduce_max(float v, float* red4) {
  __syncthreads();
  for (int m = 32; m >= 1; m >>= 1) v = fmaxf(v, __shfl_down(v, m, 64));
  int lane = threadIdx.x & 63, wid = threadIdx.x >> 6;
  if (lane == 0) red4[wid] = v;
  __syncthreads();
  return fmaxf(fmaxf(red4[0], red4[1]), fmaxf(red4[2], red4[3]));
}

// sum the NPART stat partials for (t,b): layout sp[t][part][b][2]
__device__ inline void stat_sum8(const float* __restrict__ sp, int t, int b,
                                 float& a, float& c) {
  a = 0.f; c = 0.f;
  const float* p = sp + (((size_t)t * NPART) * BB + b) * 2;
  #pragma unroll
  for (int i = 0; i < NPART; ++i) {
    float2 v = *(const float2*)(p + (size_t)i * BB * 2);
    a += v.x; c += v.y;
  }
}

// ---------------- setup kernels -------------------------------------------

__global__ __launch_bounds__(256) void k_sig(float* out, int n) {
  int i = blockIdx.x * 256 + threadIdx.x;
  if (i < n) out[i] = 7.0f;   // "workspace too small" signature
}

__global__ __launch_bounds__(256) void k_ln_x(const float* __restrict__ x,
    const float* __restrict__ g, const float* __restrict__ be,
    f16* __restrict__ xn) {
  __shared__ float red4[4];
  int row = blockIdx.x;            // row = t*BB + b
  int t = row >> 6, b = row & 63;
  const float* xr = x + ((size_t)b * NT + t) * EE;
  float vals[3]; float p = 0.f, p2 = 0.f;
  #pragma unroll
  for (int i = 0; i < 3; ++i) {
    int k = threadIdx.x + 256 * i;
    vals[i] = xr[k]; p += vals[i]; p2 += vals[i] * vals[i];
  }
  float s = block_reduce_sum(p, red4);
  float s2 = block_reduce_sum(p2, red4);
  float mu = s * (1.f / EE);
  float r = rsqrtf(fmaxf(s2 * (1.f / EE) - mu * mu, 0.f) + EPS);
  #pragma unroll
  for (int i = 0; i < 3; ++i) {
    int k = threadIdx.x + 256 * i;
    xn[(size_t)row * EE + k] = (f16)((vals[i] - mu) * r * g[k] + be[k]);
  }
}

__global__ __launch_bounds__(256) void k_cast(f16* __restrict__ dst,
    const float* __restrict__ src, int rows, int cols, int ldd,
    const float* __restrict__ scale) {
  int r = blockIdx.x;
  for (int c = threadIdx.x; c < ldd; c += 256) {
    float v = 0.f;
    if (r < rows && c < cols) {
      v = src[(size_t)r * cols + c];
      if (scale) v *= scale[c];
    }
    dst[(size_t)r * ldd + c] = (f16)v;
  }
}

__global__ __launch_bounds__(256) void k_castT(f16* __restrict__ dst,
    const float* __restrict__ src, int srcRows, int srcCols, int ldd) {
  __shared__ float tile[32][33];
  int jb = blockIdx.x * 32;
  int nb = blockIdx.y * 32;
  int tx = threadIdx.x & 31, ty = threadIdx.x >> 5;
  for (int i = ty; i < 32; i += 8) {
    int sr = nb + i, sc = jb + tx;
    tile[i][tx] = (sr < srcRows && sc < srcCols) ? src[(size_t)sr * srcCols + sc] : 0.f;
  }
  __syncthreads();
  for (int i = ty; i < 32; i += 8) {
    dst[(size_t)(jb + i) * ldd + (nb + tx)] = (f16)tile[tx][i];
  }
}

__global__ __launch_bounds__(256) void k_rowdot(const float* __restrict__ src,
    const float* __restrict__ g, const float* __restrict__ be,
    int rows, int cols, float* __restrict__ Ev, float* __restrict__ Dv) {
  __shared__ float red4[4];
  int r = blockIdx.x;
  float pe = 0.f, pd = 0.f;
  if (r < rows) {
    for (int k = threadIdx.x; k < cols; k += 256) {
      float w = src[(size_t)r * cols + k];
      pe += w * g[k]; pd += w * be[k];
    }
  }
  float e = block_reduce_sum(pe, red4);
  float d = block_reduce_sum(pd, red4);
  if (threadIdx.x == 0) { Ev[r] = (r < rows) ? e : 0.f; Dv[r] = (r < rows) ? d : 0.f; }
}

__global__ __launch_bounds__(256) void k_addvec(const float* a, const float* b,
    int N, int NP, float* outv) {
  int i = blockIdx.x * 256 + threadIdx.x;
  if (i < NP) outv[i] = (i < N) ? a[i] + b[i] : 0.f;
}

// ---------------- generic f16 MFMA GEMM (post-scan use) -------------------
__global__ __launch_bounds__(256) void k_gemm(const f16* __restrict__ A, int lda,
    const f16* __restrict__ Bw, int ldb, float* __restrict__ C, int ldc,
    int Nvalid, int K, const float* __restrict__ bias, int accFlag) {
  int tid = threadIdx.x, w = tid >> 6, lid = tid & 63;
  int l15 = lid & 15, lhi = lid >> 4;
  int m0 = blockIdx.y * 64 + 16 * w;
  int n0 = blockIdx.x * 64;
  const f16* Ap = A + ((size_t)(m0 + l15)) * lda + lhi * 8;
  const f16* Bp = Bw + ((size_t)(n0 + l15)) * ldb + lhi * 8;
  f32x4 acc[4];
  #pragma unroll
  for (int j = 0; j < 4; ++j) acc[j] = (f32x4){0.f, 0.f, 0.f, 0.f};
  for (int k = 0; k < K; k += 32) {
    f16x8 a = *(const f16x8*)(Ap + k);
    #pragma unroll
    for (int j = 0; j < 4; ++j) {
      f16x8 b = *(const f16x8*)(Bp + (size_t)16 * j * ldb + k);
      acc[j] = mfma16(a, b, acc[j]);
    }
  }
  #pragma unroll
  for (int j = 0; j < 4; ++j) {
    int col = n0 + 16 * j + l15;
    #pragma unroll
    for (int q = 0; q < 4; ++q) {
      int row = m0 + lhi * 4 + q;
      float v = acc[j][q];
      if (bias && col < Nvalid) v += bias[col];
      size_t ci = (size_t)row * ldc + col;
      if (accFlag) v += C[ci];
      C[ci] = v;
    }
  }
}

__global__ __launch_bounds__(256) void k_gemm_h(const f16* __restrict__ A, int lda,
    const f16* __restrict__ Bw, int ldb, f16* __restrict__ C, int ldc,
    int Nvalid, int K, const float* __restrict__ bias) {
  int tid = threadIdx.x, w = tid >> 6, lid = tid & 63;
  int l15 = lid & 15, lhi = lid >> 4;
  int m0 = blockIdx.y * 64 + 16 * w;
  int n0 = blockIdx.x * 64;
  const f16* Ap = A + ((size_t)(m0 + l15)) * lda + lhi * 8;
  const f16* Bp = Bw + ((size_t)(n0 + l15)) * ldb + lhi * 8;
  f32x4 acc[4];
  #pragma unroll
  for (int j = 0; j < 4; ++j) acc[j] = (f32x4){0.f, 0.f, 0.f, 0.f};
  for (int k = 0; k < K; k += 32) {
    f16x8 a = *(const f16x8*)(Ap + k);
    #pragma unroll
    for (int j = 0; j < 4; ++j) {
      f16x8 b = *(const f16x8*)(Bp + (size_t)16 * j * ldb + k);
      acc[j] = mfma16(a, b, acc[j]);
    }
  }
  #pragma unroll
  for (int j = 0; j < 4; ++j) {
    int col = n0 + 16 * j + l15;
    #pragma unroll
    for (int q = 0; q < 4; ++q) {
      int row = m0 + lhi * 4 + q;
      float v = acc[j][q];
      if (bias && col < Nvalid) v += bias[col];
      C[(size_t)row * ldc + col] = (f16)v;
    }
  }
}

// ---------------- persistent scan kernel ----------------------------------

__device__ inline void gridbar(unsigned int* bar) {
  __syncthreads();
  if (threadIdx.x == 0) {
    __threadfence();
    unsigned int g = __hip_atomic_load(bar + 1, __ATOMIC_RELAXED, __HIP_MEMORY_SCOPE_AGENT);
    unsigned int c = __hip_atomic_fetch_add(bar, 1u, __ATOMIC_ACQ_REL, __HIP_MEMORY_SCOPE_AGENT);
    if (c == (unsigned int)(NBLK - 1)) {
      __hip_atomic_store(bar, 0u, __ATOMIC_RELAXED, __HIP_MEMORY_SCOPE_AGENT);
      __hip_atomic_fetch_add(bar + 1, 1u, __ATOMIC_RELEASE, __HIP_MEMORY_SCOPE_AGENT);
    } else {
      while (__hip_atomic_load(bar + 1, __ATOMIC_RELAXED, __HIP_MEMORY_SCOPE_AGENT) == g)
        __builtin_amdgcn_s_sleep(8);
    }
    __threadfence();   // acquire: makes other blocks' writes visible
  }
  __syncthreads();
}

// K=2368 (37 chunks of 64): depth-8 A-ring (global), depth-2 B-ring (LDS)
__device__ __forceinline__ void gemm37(const f16* __restrict__ Ap, const f16* Bp,
                                       f32x4& acc0, f32x4& acc1) {
  f16x8 ab[8][2];
  #pragma unroll
  for (int d = 0; d < 8; ++d) {
    ab[d][0] = *(const f16x8*)(Ap + d * 64);
    ab[d][1] = *(const f16x8*)(Ap + d * 64 + 32);
  }
  f16x8 bb[2][2];
  #pragma unroll
  for (int d = 0; d < 2; ++d) {
    bb[d][0] = *(const f16x8*)(Bp + d * 64);
    bb[d][1] = *(const f16x8*)(Bp + d * 64 + 32);
  }
  #pragma unroll 1
  for (int g = 0; g < 3; ++g) {
    const int kc0 = g * 8;
    #pragma unroll
    for (int d = 0; d < 8; ++d) {
      acc0 = mfma16(ab[d][0], bb[d & 1][0], acc0);
      acc1 = mfma16(ab[d][1], bb[d & 1][1], acc1);
      ab[d][0] = *(const f16x8*)(Ap + (kc0 + d + 8) * 64);
      ab[d][1] = *(const f16x8*)(Ap + (kc0 + d + 8) * 64 + 32);
      bb[d & 1][0] = *(const f16x8*)(Bp + (kc0 + d + 2) * 64);
      bb[d & 1][1] = *(const f16x8*)(Bp + (kc0 + d + 2) * 64 + 32);
    }
  }
  #pragma unroll
  for (int d = 0; d < 8; ++d) {     // kc = 24+d, prefetch A 32..36, B 26..33
    acc0 = mfma16(ab[d][0], bb[d & 1][0], acc0);
    acc1 = mfma16(ab[d][1], bb[d & 1][1], acc1);
    if (d < 5) {
      ab[d][0] = *(const f16x8*)(Ap + (32 + d) * 64);
      ab[d][1] = *(const f16x8*)(Ap + (32 + d) * 64 + 32);
    }
    bb[d & 1][0] = *(const f16x8*)(Bp + (26 + d) * 64);
    bb[d & 1][1] = *(const f16x8*)(Bp + (26 + d) * 64 + 32);
  }
  #pragma unroll
  for (int d = 0; d < 5; ++d) {     // kc = 32+d
    acc0 = mfma16(ab[d][0], bb[d & 1][0], acc0);
    acc1 = mfma16(ab[d][1], bb[d & 1][1], acc1);
    if (d < 3) {
      bb[d & 1][0] = *(const f16x8*)(Bp + (34 + d) * 64);
      bb[d & 1][1] = *(const f16x8*)(Bp + (34 + d) * 64 + 32);
    }
  }
}

// K=768 (12 chunks of 64)
__device__ __forceinline__ void gemm12(const f16* __restrict__ Ap, const f16* Bp,
                                       f32x4& acc0, f32x4& acc1) {
  f16x8 ab[8][2];
  #pragma unroll
  for (int d = 0; d < 8; ++d) {
    ab[d][0] = *(const f16x8*)(Ap + d * 64);
    ab[d][1] = *(const f16x8*)(Ap + d * 64 + 32);
  }
  f16x8 bb[2][2];
  #pragma unroll
  for (int d = 0; d < 2; ++d) {
    bb[d][0] = *(const f16x8*)(Bp + d * 64);
    bb[d][1] = *(const f16x8*)(Bp + d * 64 + 32);
  }
  #pragma unroll
  for (int d = 0; d < 4; ++d) {     // kc = d
    acc0 = mfma16(ab[d][0], bb[d & 1][0], acc0);
    acc1 = mfma16(ab[d][1], bb[d & 1][1], acc1);
    ab[d][0] = *(const f16x8*)(Ap + (d + 8) * 64);
    ab[d][1] = *(const f16x8*)(Ap + (d + 8) * 64 + 32);
    bb[d & 1][0] = *(const f16x8*)(Bp + (d + 2) * 64);
    bb[d & 1][1] = *(const f16x8*)(Bp + (d + 2) * 64 + 32);
  }
  #pragma unroll
  for (int d = 4; d < 8; ++d) {     // kc = d
    acc0 = mfma16(ab[d][0], bb[d & 1][0], acc0);
    acc1 = mfma16(ab[d][1], bb[d & 1][1], acc1);
    bb[d & 1][0] = *(const f16x8*)(Bp + (d + 2) * 64);
    bb[d & 1][1] = *(const f16x8*)(Bp + (d + 2) * 64 + 32);
  }
  #pragma unroll
  for (int d = 0; d < 4; ++d) {     // kc = 8+d
    acc0 = mfma16(ab[d][0], bb[d & 1][0], acc0);
    acc1 = mfma16(ab[d][1], bb[d & 1][1], acc1);
    if (d < 2) {
      bb[d & 1][0] = *(const f16x8*)(Bp + (10 + d) * 64);
      bb[d & 1][1] = *(const f16x8*)(Bp + (10 + d) * 64 + 32);
    }
  }
}

__global__ __launch_bounds__(512, 1) void k_scan(
    const f16* __restrict__ XW1,
    const f16* __restrict__ W1g, const float* __restrict__ E1v, const float* __restrict__ D1v,
    const f16* __restrict__ W2g, const float* __restrict__ E2v, const float* __restrict__ D2v,
    const f16* __restrict__ Whg, const float* __restrict__ Ehv, const float* __restrict__ Dhv,
    const float* __restrict__ bih2, const float* __restrict__ bhh2,
    f16* __restrict__ hist1, f16* __restrict__ hist2,
    float* __restrict__ stats1p, float* __restrict__ stats2p,
    const int* __restrict__ sl, unsigned int* __restrict__ bar) {
  __shared__ __align__(16) char smem[152064];
  const int blk = blockIdx.x;
  const int tid = threadIdx.x;
  const int w = tid >> 6;
  const int lid = tid & 63;
  const int l15 = lid & 15;
  const int lhi = lid >> 4;
  const int part = blk & (NPART - 1);

  if (blk < NZ1) {
    // ================= cell-1 block: 32 output cols =================
    f16* Bsh = (f16*)smem;                     // [32][BP]
    const int n0b = blk * 32;
    for (int idx = tid; idx < 32 * 296; idx += 512) {
      int r = idx / 296, c = (idx % 296) * 8;
      *(f16x8*)(Bsh + (size_t)r * BP + c) = *(const f16x8*)(W1g + (size_t)(n0b + r) * HP + c);
    }
    __syncthreads();

    const int cg = w >> 2;                     // col group 0/1
    const int m0 = 16 * (w & 3);               // row group
    const int col = n0b + 16 * cg + l15;
    const f16* Bp = Bsh + (size_t)(16 * cg + l15) * BP + lhi * 8;
    const float e1 = E1v[col], d1 = D1v[col];
    int slb_[4];
    #pragma unroll
    for (int q = 0; q < 4; ++q) slb_[q] = sl[m0 + lhi * 4 + q];

    for (int t = 0; t <= NT; ++t) {
      if (t < NT) {
        const size_t tm1 = (t > 0) ? (size_t)(t - 1) : 0;
        float xw_[4]; f16 old_[4]; float s1s[4], s2s[4];
        #pragma unroll
        for (int q = 0; q < 4; ++q) {
          const int b = m0 + lhi * 4 + q;
          xw_[q] = (float)XW1[((size_t)t * BB + b) * HP + col];
          old_[q] = hist1[(tm1 * BB + b) * HP + col];
          s1s[q] = 0.f; s2s[q] = 0.f;
          if (t > 0) {
            const int ts = min(t - 1, slb_[q] - 1);
            const float* pp = stats1p + (((size_t)ts * NPART) * BB + b) * 2;
            #pragma unroll
            for (int p = 0; p < NPART; ++p) {
              float2 v2 = *(const float2*)(pp + (size_t)p * BB * 2);
              s1s[q] += v2.x; s2s[q] += v2.y;
            }
          }
        }
        f32x4 acc0 = {0.f,0.f,0.f,0.f}, acc1 = {0.f,0.f,0.f,0.f};
        if (t > 0) {
          gemm37(hist1 + (tm1 * BB + m0 + l15) * HP + lhi * 8, Bp, acc0, acc1);
        }
        float sv[4], qv[4]; bool act_[4];
        #pragma unroll
        for (int q = 0; q < 4; ++q) {
          const int b = m0 + lhi * 4 + q;
          const bool active = (t < slb_[q]);
          float v;
          if (t == 0) {
            v = xw_[q];
          } else {
            const float accq = acc0[q] + acc1[q];
            const float mu = s1s[q] * (1.f / HH);
            const float r = rsqrtf(fmaxf(s2s[q] * (1.f / HH) - mu * mu, 0.f) + EPS);
            v = r * accq - mu * r * e1 + d1 + xw_[q];
          }
          float tau = tanhf(v);
          if (col >= HH) tau = 0.f;
          const f16 st = active ? (f16)tau : old_[q];
          hist1[((size_t)t * BB + b) * HP + col] = st;
          const float tq = active ? (float)st : 0.f;
          sv[q] = tq; qv[q] = tq * tq; act_[q] = active;
        }
        #pragma unroll
        for (int m = 1; m <= 8; m <<= 1) {
          #pragma unroll
          for (int q = 0; q < 4; ++q) {
            sv[q] += __shfl_xor(sv[q], m, 64);
            qv[q] += __shfl_xor(qv[q], m, 64);
          }
        }
        if (l15 == 0) {
          #pragma unroll
          for (int q = 0; q < 4; ++q) if (act_[q]) {
            const int b = m0 + lhi * 4 + q;
            atomicAdd(&stats1p[(((size_t)t * NPART + part) * BB + b) * 2 + 0], sv[q]);
            atomicAdd(&stats1p[(((size_t)t * NPART + part) * BB + b) * 2 + 1], qv[q]);
          }
        }
      }
      gridbar(bar);
    }
  } else {
    // ================= cell-2 block: 16 output cols =================
    f16* W2s = (f16*)smem;                         // [16][BP]
    f16* Whs = (f16*)(smem + 76032);               // [16][WP]
    float* partB = (float*)(smem + 100864);        // [4][16][17]
    const int n0 = (blk - NZ1) * 16;
    for (int idx = tid; idx < 16 * 296; idx += 512) {
      int r = idx / 296, c = (idx % 296) * 8;
      *(f16x8*)(W2s + (size_t)r * BP + c) = *(const f16x8*)(W2g + (size_t)(n0 + r) * HP + c);
    }
    for (int idx = tid; idx < 16 * 96; idx += 512) {
      int r = idx / 96, c = (idx % 96) * 8;
      *(f16x8*)(Whs + (size_t)r * WP + c) = *(const f16x8*)(Whg + (size_t)(n0 + r) * EP + c);
    }
    __syncthreads();

    const int col = n0 + l15;
    const int m0 = 16 * (w & 3);
    const float e2 = E2v[col], d2 = D2v[col], eh = Ehv[col], dh = Dhv[col];
    const float bsum2 = bih2[col] + bhh2[col];
    int slb_[4];
    #pragma unroll
    for (int q = 0; q < 4; ++q) slb_[q] = sl[m0 + lhi * 4 + q];

    for (int t = 0; t <= NT; ++t) {
      if (t >= 1) {
        const int s = t - 1;
        f32x4 acc0 = {0.f,0.f,0.f,0.f}, acc1 = {0.f,0.f,0.f,0.f};
        f16 old_[4]; float s1s[4], s2s[4], u1s[4], u2s[4];
        if (w >= 4) {
          // cell2B: h2_{s-1} @ Whh2g^T
          f32x4 aB0 = {0.f,0.f,0.f,0.f}, aB1 = {0.f,0.f,0.f,0.f};
          if (s >= 1) {
            gemm12(hist2 + (((size_t)(s - 1)) * BB + 16 * (w - 4) + l15) * EP + lhi * 8,
                   Whs + (size_t)l15 * WP + lhi * 8, aB0, aB1);
          }
          #pragma unroll
          for (int q = 0; q < 4; ++q)
            partB[((w - 4) * 16 + lhi * 4 + q) * 17 + l15] = aB0[q] + aB1[q];
        } else {
          // early loads
          const size_t sm1 = (s > 0) ? (size_t)(s - 1) : 0;
          #pragma unroll
          for (int q = 0; q < 4; ++q) {
            const int b = m0 + lhi * 4 + q;
            old_[q] = hist2[(sm1 * BB + b) * EP + col];
            s1s[q] = s2s[q] = u1s[q] = u2s[q] = 0.f;
            {
              const float* pp = stats1p + (((size_t)s * NPART) * BB + b) * 2;
              #pragma unroll
              for (int p = 0; p < NPART; ++p) {
                float2 v2 = *(const float2*)(pp + (size_t)p * BB * 2);
                s1s[q] += v2.x; s2s[q] += v2.y;
              }
            }
            if (s >= 1) {
              const int t2 = min(s - 1, slb_[q] - 1);
              const float* pp = stats2p + (((size_t)t2 * NPART) * BB + b) * 2;
              #pragma unroll
              for (int p = 0; p < NPART; ++p) {
                float2 v2 = *(const float2*)(pp + (size_t)p * BB * 2);
                u1s[q] += v2.x; u2s[q] += v2.y;
              }
            }
          }
          // cell2A: h1n_s @ Wih2g^T
          gemm37(hist1 + ((size_t)s * BB + m0 + l15) * HP + lhi * 8,
                 W2s + (size_t)l15 * BP + lhi * 8, acc0, acc1);
        }
        __syncthreads();
        if (w < 4) {
          float sv[4], qv[4]; bool act_[4];
          #pragma unroll
          for (int q = 0; q < 4; ++q) {
            const int b = m0 + lhi * 4 + q;
            const bool active = (s < slb_[q]);
            const float accA = acc0[q] + acc1[q];
            const float mu1 = s1s[q] * (1.f / HH);
            const float r1 = rsqrtf(fmaxf(s2s[q] * (1.f / HH) - mu1 * mu1, 0.f) + EPS);
            float v = r1 * accA - mu1 * r1 * e2 + d2 + bsum2;
            if (s >= 1) {
              const float accB = partB[(w * 16 + lhi * 4 + q) * 17 + l15];
              const float mu2 = u1s[q] * (1.f / EE);
              const float r2 = rsqrtf(fmaxf(u2s[q] * (1.f / EE) - mu2 * mu2, 0.f) + EPS);
              v += r2 * accB - mu2 * r2 * eh + dh;
            }
            float tau = tanhf(v);
            const f16 st = active ? (f16)tau : old_[q];
            hist2[((size_t)s * BB + b) * EP + col] = st;
            const float tq = active ? (float)st : 0.f;
            sv[q] = tq; qv[q] = tq * tq; act_[q] = active;
          }
          #pragma unroll
          for (int m = 1; m <= 8; m <<= 1) {
            #pragma unroll
            for (int q = 0; q < 4; ++q) {
              sv[q] += __shfl_xor(sv[q], m, 64);
              qv[q] += __shfl_xor(qv[q], m, 64);
            }
          }
          if (l15 == 0) {
            #pragma unroll
            for (int q = 0; q < 4; ++q) if (act_[q]) {
              const int b = m0 + lhi * 4 + q;
              atomicAdd(&stats2p[(((size_t)s * NPART + part) * BB + b) * 2 + 0], sv[q]);
              atomicAdd(&stats2p[(((size_t)s * NPART + part) * BB + b) * 2 + 1], qv[q]);
            }
          }
        }
      }
      gridbar(bar);
    }
  }
}

// ---------------- post-scan kernels ---------------------------------------

__global__ __launch_bounds__(256) void k_gather(
    const f16* __restrict__ hist1, const float* __restrict__ stats1p,
    const f16* __restrict__ hist2, const float* __restrict__ stats2p,
    const f16* __restrict__ XW1, const int* __restrict__ sl,
    const float* __restrict__ g1, const float* __restrict__ be1,
    const float* __restrict__ g2, const float* __restrict__ be2,
    f16* __restrict__ hq1, f16* __restrict__ hq2, float* __restrict__ u1) {
  int sec = blockIdx.x >> 6, b = blockIdx.x & 63;
  int tb = sl[b] - 1;
  if (sec == 0) {
    float s1, s2; stat_sum8(stats1p, tb, b, s1, s2);
    float mu = s1 * (1.f / HH);
    float r = rsqrtf(fmaxf(s2 * (1.f / HH) - mu * mu, 0.f) + EPS);
    for (int k = threadIdx.x; k < HP; k += 256) {
      float h = 0.f;
      if (k < HH) h = ((float)hist1[((size_t)tb * BB + b) * HP + k] - mu) * r * g1[k] + be1[k];
      hq1[(size_t)b * HP + k] = (f16)h;
    }
  } else if (sec == 1) {
    float s1, s2; stat_sum8(stats2p, tb, b, s1, s2);
    float mu = s1 * (1.f / EE);
    float r = rsqrtf(fmaxf(s2 * (1.f / EE) - mu * mu, 0.f) + EPS);
    for (int k = threadIdx.x; k < EP; k += 256) {
      float h = ((float)hist2[((size_t)tb * BB + b) * EP + k] - mu) * r * g2[k] + be2[k];
      hq2[(size_t)b * EP + k] = (f16)h;
    }
  } else {
    for (int n = threadIdx.x; n < HP; n += 256)
      u1[(size_t)b * HP + n] = (float)XW1[((size_t)tb * BB + b) * HP + n];
  }
}

__global__ __launch_bounds__(256) void k_cast64(const float* __restrict__ src,
    f16* __restrict__ dst, int N, int ld) {
  int b = blockIdx.x;
  for (int k = threadIdx.x; k < ld; k += 256)
    dst[(size_t)b * ld + k] = (f16)((k < N) ? src[(size_t)b * ld + k] : 0.f);
}

__global__ __launch_bounds__(256) void k_qg(const float* __restrict__ qk, int ld,
    const float* __restrict__ g, int N, float* __restrict__ qg, float* __restrict__ S0) {
  __shared__ float red4[4];
  int b = blockIdx.x;
  float p = 0.f;
  for (int k = threadIdx.x; k < ld; k += 256) {
    float v = (k < N) ? qk[(size_t)b * ld + k] * g[k] : 0.f;
    qg[(size_t)b * ld + k] = v;
    p += v;
  }
  float s = block_reduce_sum(p, red4);
  if (threadIdx.x == 0) S0[b] = s;
}

__global__ __launch_bounds__(256) void k_scores(const float* __restrict__ qg, int ldq,
    const f16* __restrict__ hist, int ldh, const float* __restrict__ statsp,
    const float* __restrict__ S0, const int* __restrict__ sl, int N, float invsqd,
    float* __restrict__ scores) {
  __shared__ float red4[4];
  int s = blockIdx.x, b = blockIdx.y;
  const float* qrow = qg + (size_t)b * ldq;
  const f16* hrow = hist + ((size_t)s * BB + b) * ldh;
  float p = 0.f;
  for (int k = threadIdx.x; k < N; k += 256) p += qrow[k] * (float)hrow[k];
  float dot = block_reduce_sum(p, red4);
  if (threadIdx.x == 0) {
    int ss = min(s, sl[b] - 1);
    float s1, s2; stat_sum8(statsp, ss, b, s1, s2);
    float mu = s1 / N;
    float r = rsqrtf(fmaxf(s2 / N - mu * mu, 0.f) + EPS);
    scores[(size_t)b * NT + s] = (r * dot - r * mu * S0[b]) * invsqd;
  }
}

__global__ __launch_bounds__(256) void k_softmax(const float* __restrict__ scores,
    const float* __restrict__ statsp, const int* __restrict__ sl, int N,
    float* __restrict__ aw, float* __restrict__ cb) {
  __shared__ float red4[4];
  int b = blockIdx.x, s = threadIdx.x;
  float sc = scores[(size_t)b * NT + s];
  float m = block_reduce_max(sc, red4);
  float e = expf(sc - m);
  float Z = block_reduce_sum(e, red4);
  float a = e / Z;
  int ss = min(s, sl[b] - 1);
  float s1, s2; stat_sum8(statsp, ss, b, s1, s2);
  float mu = s1 / N;
  float r = rsqrtf(fmaxf(s2 / N - mu * mu, 0.f) + EPS);
  aw[(size_t)b * NT + s] = a * r;
  float c = block_reduce_sum(a * r * mu, red4);
  if (threadIdx.x == 0) cb[b] = c;
}

__global__ __launch_bounds__(256) void k_wsum(const f16* __restrict__ hist, int ldh,
    const float* __restrict__ aw, const float* __restrict__ cb,
    const float* __restrict__ g, const float* __restrict__ be, int N,
    f16* __restrict__ out, int ldo) {
  __shared__ float awS[NT];
  int b = blockIdx.y;
  int k = blockIdx.x * 256 + threadIdx.x;
  awS[threadIdx.x] = aw[(size_t)b * NT + threadIdx.x];
  __syncthreads();
  if (k >= ldo) return;
  float acc = 0.f;
  const f16* hb = hist + (size_t)b * ldh + k;
  for (int s = 0; s < NT; ++s) acc += awS[s] * (float)hb[(size_t)s * BB * ldh];
  float o = (k < N) ? g[k] * (acc - cb[b]) + be[k] : 0.f;
  out[(size_t)b * ldo + k] = (f16)o;
}

__global__ __launch_bounds__(256) void k_lnrow(const float* __restrict__ u, int ldu,
    int N, const float* __restrict__ g, const float* __restrict__ be,
    f16* __restrict__ outH, float* __restrict__ outF, int ldo) {
  __shared__ float tl[HP];
  __shared__ float red4[4];
  int b = blockIdx.x;
  float p = 0.f, p2 = 0.f;
  for (int k = threadIdx.x; k < N; k += 256) {
    float tau = tanhf(u[(size_t)b * ldu + k]);
    tl[k] = tau; p += tau; p2 += tau * tau;
  }
  float s = block_reduce_sum(p, red4);
  float s2 = block_reduce_sum(p2, red4);
  float mu = s / N;
  float r = rsqrtf(fmaxf(s2 / N - mu * mu, 0.f) + EPS);
  __syncthreads();
  for (int k = threadIdx.x; k < ldo; k += 256) {
    float h = (k < N) ? (tl[k] - mu) * r * g[k] + be[k] : 0.f;
    if (outH) outH[(size_t)b * ldo + k] = (f16)h;
    else outF[(size_t)b * ldo + k] = h;
  }
}

__global__ __launch_bounds__(256) void k_logits(const float* __restrict__ h2,
    const float* __restrict__ Wc, const float* __restrict__ bc, float* __restrict__ out) {
  __shared__ float hrow[EP];
  __shared__ float red4[4];
  int b = blockIdx.x;
  for (int k = threadIdx.x; k < EP; k += 256) hrow[k] = h2[(size_t)b * EP + k];
  __syncthreads();
  for (int o = 0; o < OO; ++o) {
    float p = 0.f;
    for (int k = threadIdx.x; k < EP; k += 256) p += hrow[k] * Wc[(size_t)o * EP + k];
    float v = block_reduce_sum(p, red4);
    if (threadIdx.x == 0) {
      v += bc[o];
      out[(size_t)b * OO + o] = fminf(fmaxf(v, -10.f), 10.f);
    }
  }
}

// ---------------------------------------------------------------------------

extern "C" void kernel_launch(void* const* d_in, const int* in_sizes, int n_in,
                              void* d_out, int out_size, void* d_ws, size_t ws_size,
                              hipStream_t stream) {
  const float* x     = (const float*)d_in[0];
  const int*   sl    = (const int*)d_in[1];
  const float* in_g  = (const float*)d_in[2];
  const float* in_b  = (const float*)d_in[3];
  const float* Wih1  = (const float*)d_in[4];
  const float* bih1  = (const float*)d_in[5];
  const float* Whh1  = (const float*)d_in[6];
  const float* bhh1  = (const float*)d_in[7];
  const float* g1    = (const float*)d_in[8];
  const float* be1   = (const float*)d_in[9];
  const float* Wih2  = (const float*)d_in[10];
  const float* bih2  = (const float*)d_in[11];
  const float* Whh2  = (const float*)d_in[12];
  const float* bhh2  = (const float*)d_in[13];
  const float* g2    = (const float*)d_in[14];
  const float* be2   = (const float*)d_in[15];
  const float* Wqkv1 = (const float*)d_in[16];
  const float* bqkv1 = (const float*)d_in[17];
  const float* Wo1w  = (const float*)d_in[18];
  const float* bo1   = (const float*)d_in[19];
  const float* Wqkv2 = (const float*)d_in[20];
  const float* bqkv2 = (const float*)d_in[21];
  const float* Wo2w  = (const float*)d_in[22];
  const float* bo2   = (const float*)d_in[23];
  const float* Wc    = (const float*)d_in[24];
  const float* bc    = (const float*)d_in[25];
  float* outp = (float*)d_out;

  char* base = (char*)d_ws;
  size_t off = 0;
  auto alloc = [&](size_t bytes) -> void* {
    void* p = base + off;
    off = (off + bytes + 255) & ~(size_t)255;
    return p;
  };
  // --- persistent (scan-lifetime) buffers ---
  float* stats1p = (float*)alloc((size_t)NT * NPART * BB * 2 * 4);  // 1 MB
  float* stats2p = (float*)alloc((size_t)NT * NPART * BB * 2 * 4);  // 1 MB
  unsigned int* bar = (unsigned int*)alloc(256);
  f16* XW1h  = (f16*)alloc((size_t)NT * BB * HP * 2);   // 77.6 MB
  f16* hist1 = (f16*)alloc((size_t)NT * BB * HP * 2);   // 77.6 MB
  f16* hist2 = (f16*)alloc((size_t)NT * BB * EP * 2);   // 25.2 MB
  f16* W1g   = (f16*)alloc((size_t)HP * HP * 2);        // 11.2 MB (reused post-scan)
  f16* W2g   = (f16*)alloc((size_t)EP * HP * 2);        //  3.6 MB (reused post-scan)
  f16* Whg   = (f16*)alloc((size_t)EP * EP * 2);        //  1.2 MB
  float* E1v = (float*)alloc(HP * 4);
  float* D1v = (float*)alloc(HP * 4);
  float* E2v = (float*)alloc(EP * 4);
  float* D2v = (float*)alloc(EP * 4);
  float* Ehv = (float*)alloc(EP * 4);
  float* Dhv = (float*)alloc(EP * 4);
  float* bsum1 = (float*)alloc(HP * 4);

  // --- reuse region R: pre-scan {xnh, Wih1h}; post-scan activation smalls ---
  char* R = (char*)alloc((size_t)29 * 1024 * 1024);
  f16* xnh   = (f16*)R;                                  // 25,165,824 B
  f16* Wih1h = (f16*)(R + 25165824);                     //  3,637,248 B
  size_t ro = 0;
  auto ralloc = [&](size_t bytes) -> void* {
    void* p = R + ro;
    ro = (ro + bytes + 255) & ~(size_t)255;
    return p;
  };
  f16* hq1in = (f16*)ralloc((size_t)BB * HP * 2);
  f16* hq2in = (f16*)ralloc((size_t)BB * EP * 2);
  float* q1   = (float*)ralloc((size_t)BB * HP * 4);
  f16* q1h    = (f16*)ralloc((size_t)BB * HP * 2);
  float* qk1  = (float*)ralloc((size_t)BB * HP * 4);
  float* qg1  = (float*)ralloc((size_t)BB * HP * 4);
  float* S01  = (float*)ralloc(BB * 4);
  float* scores1 = (float*)ralloc((size_t)BB * NT * 4);
  float* aw1 = (float*)ralloc((size_t)BB * NT * 4);
  float* c1v = (float*)ralloc(BB * 4);
  f16* wsum1h = (f16*)ralloc((size_t)BB * HP * 2);
  float* out1 = (float*)ralloc((size_t)BB * HP * 4);
  f16* out1h = (f16*)ralloc((size_t)BB * HP * 2);
  float* mha1 = (float*)ralloc((size_t)BB * HP * 4);
  f16* mha1h = (f16*)ralloc((size_t)BB * HP * 2);
  float* q2   = (float*)ralloc((size_t)BB * EP * 4);
  f16* q2h    = (f16*)ralloc((size_t)BB * EP * 2);
  float* qk2  = (float*)ralloc((size_t)BB * EP * 4);
  float* qg2  = (float*)ralloc((size_t)BB * EP * 4);
  float* S02  = (float*)ralloc(BB * 4);
  float* scores2 = (float*)ralloc((size_t)BB * NT * 4);
  float* aw2 = (float*)ralloc((size_t)BB * NT * 4);
  float* c2v = (float*)ralloc(BB * 4);
  f16* wsum2h = (f16*)ralloc((size_t)BB * EP * 2);
  float* out2 = (float*)ralloc((size_t)BB * EP * 4);
  f16* out2h = (f16*)ralloc((size_t)BB * EP * 2);
  float* mha2 = (float*)ralloc((size_t)BB * EP * 4);
  f16* mha2h = (f16*)ralloc((size_t)BB * EP * 2);
  float* u1 = (float*)ralloc((size_t)BB * HP * 4);
  f16* h1nh = (f16*)ralloc((size_t)BB * HP * 2);
  float* u2 = (float*)ralloc((size_t)BB * EP * 4);
  float* h2nf = (float*)ralloc((size_t)BB * EP * 4);

  // post-scan weight aliases (sequential use, cast-before-each-GEMM):
  f16* Wbig = W1g;   // Wq1 -> WkT1 -> Wv1 -> Wo1 -> Whh1 in turn
  f16* Wsm  = W2g;   // Wq2 -> WkT2 -> Wv2 -> Wo2 -> Wih2 -> Whh2 in turn

  if (off > ws_size) {  // workspace too small: emit diagnostic signature
    k_sig<<<(out_size + 255) / 256, 256, 0, stream>>>(outp, out_size);
    return;
  }

  hipMemsetAsync(stats1p, 0, (size_t)NT * NPART * BB * 2 * 4, stream);
  hipMemsetAsync(stats2p, 0, (size_t)NT * NPART * BB * 2 * 4, stream);
  hipMemsetAsync(bar, 0, 256, stream);

  // input LN -> f16
  k_ln_x<<<NT * BB, 256, 0, stream>>>(x, in_g, in_b, xnh);

  // scan-phase weights
  k_cast<<<HP, 256, 0, stream>>>(W1g, Whh1, HH, HH, HP, g1);
  k_cast<<<HP, 256, 0, stream>>>(Wih1h, Wih1, HH, EE, EE, nullptr);
  k_cast<<<EP, 256, 0, stream>>>(W2g, Wih2, EE, HH, HP, g1);
  k_cast<<<EP, 256, 0, stream>>>(Whg, Whh2, EE, EE, EP, g2);

  // folded-LN constant vectors
  k_rowdot<<<HP, 256, 0, stream>>>(Whh1, g1, be1, HH, HH, E1v, D1v);
  k_rowdot<<<EP, 256, 0, stream>>>(Wih2, g1, be1, EE, HH, E2v, D2v);
  k_rowdot<<<EP, 256, 0, stream>>>(Whh2, g2, be2, EE, EE, Ehv, Dhv);
  k_addvec<<<(HP + 255) / 256, 256, 0, stream>>>(bih1, bhh1, HH, HP, bsum1);

  // XW1[t,b,:] = LN(x)@Wih1^T + bih1 + bhh1  (f16; shared by both scans)
  k_gemm_h<<<dim3(HP / 64, (NT * BB) / 64), 256, 0, stream>>>(
      xnh, EE, Wih1h, EE, XW1h, HP, HH, EE, bsum1);

  // persistent scan (257 barrier-separated iterations)
  k_scan<<<NBLK, 512, 0, stream>>>(XW1h, W1g, E1v, D1v, W2g, E2v, D2v, Whg, Ehv, Dhv,
                                   bih2, bhh2, hist1, hist2, stats1p, stats2p, sl, bar);

  // gather per-batch rows at t_b = sl-1 (also frees R for post-scan smalls)
  k_gather<<<192, 256, 0, stream>>>(hist1, stats1p, hist2, stats2p, XW1h, sl,
                                    g1, be1, g2, be2, hq1in, hq2in, u1);

  const float invsq1 = 1.f / sqrtf((float)HH);
  const float invsq2 = 1.f / sqrtf((float)EE);

  // ---- MHA1 (collapsed; q.bk and qk.be1 constants drop out of softmax) ----
  k_cast<<<HP, 256, 0, stream>>>(Wbig, Wqkv1, HH, HH, HP, nullptr);              // Wq1
  k_gemm<<<dim3(37, 1), 256, 0, stream>>>(hq1in, HP, Wbig, HP, q1, HP, HH, HP, bqkv1, 0);
  k_cast64<<<BB, 256, 0, stream>>>(q1, q1h, HH, HP);
  k_castT<<<dim3(HP / 32, HP / 32), 256, 0, stream>>>(Wbig, Wqkv1 + (size_t)HH * HH, HH, HH, HP); // Wk^T
  k_gemm<<<dim3(37, 1), 256, 0, stream>>>(q1h, HP, Wbig, HP, qk1, HP, HH, HP, nullptr, 0);
  k_qg<<<BB, 256, 0, stream>>>(qk1, HP, g1, HH, qg1, S01);
  k_scores<<<dim3(NT, BB), 256, 0, stream>>>(qg1, HP, hist1, HP, stats1p, S01, sl, HH, invsq1, scores1);
  k_softmax<<<BB, 256, 0, stream>>>(scores1, stats1p, sl, HH, aw1, c1v);
  k_wsum<<<dim3((HP + 255) / 256, BB), 256, 0, stream>>>(hist1, HP, aw1, c1v, g1, be1, HH, wsum1h, HP);
  k_cast<<<HP, 256, 0, stream>>>(Wbig, Wqkv1 + (size_t)2 * HH * HH, HH, HH, HP, nullptr); // Wv1
  k_gemm<<<dim3(37, 1), 256, 0, stream>>>(wsum1h, HP, Wbig, HP, out1, HP, HH, HP,
                                          bqkv1 + (size_t)2 * HH, 0);
  k_cast64<<<BB, 256, 0, stream>>>(out1, out1h, HH, HP);
  k_cast<<<HP, 256, 0, stream>>>(Wbig, Wo1w, HH, HH, HP, nullptr);               // Wo1
  k_gemm<<<dim3(37, 1), 256, 0, stream>>>(out1h, HP, Wbig, HP, mha1, HP, HH, HP, bo1, 0);
  k_cast64<<<BB, 256, 0, stream>>>(mha1, mha1h, HH, HP);

  // ---- MHA2 (collapsed) ----
  k_cast<<<EP, 256, 0, stream>>>(Wsm, Wqkv2, EE, EE, EP, nullptr);               // Wq2
  k_gemm<<<dim3(12, 1), 256, 0, stream>>>(hq2in, EP, Wsm, EP, q2, EP, EE, EP, bqkv2, 0);
  k_cast64<<<BB, 256, 0, stream>>>(q2, q2h, EE, EP);
  k_castT<<<dim3(EP / 32, EP / 32), 256, 0, stream>>>(Wsm, Wqkv2 + (size_t)EE * EE, EE, EE, EP); // Wk^T
  k_gemm<<<dim3(12, 1), 256, 0, stream>>>(q2h, EP, Wsm, EP, qk2, EP, EE, EP, nullptr, 0);
  k_qg<<<BB, 256, 0, stream>>>(qk2, EP, g2, EE, qg2, S02);
  k_scores<<<dim3(NT, BB), 256, 0, stream>>>(qg2, EP, hist2, EP, stats2p, S02, sl, EE, invsq2, scores2);
  k_softmax<<<BB, 256, 0, stream>>>(scores2, stats2p, sl, EE, aw2, c2v);
  k_wsum<<<dim3(EP / 256, BB), 256, 0, stream>>>(hist2, EP, aw2, c2v, g2, be2, EE, wsum2h, EP);
  k_cast<<<EP, 256, 0, stream>>>(Wsm, Wqkv2 + (size_t)2 * EE * EE, EE, EE, EP, nullptr); // Wv2
  k_gemm<<<dim3(12, 1), 256, 0, stream>>>(wsum2h, EP, Wsm, EP, out2, EP, EE, EP,
                                          bqkv2 + (size_t)2 * EE, 0);
  k_cast64<<<BB, 256, 0, stream>>>(out2, out2h, EE, EP);
  k_cast<<<EP, 256, 0, stream>>>(Wsm, Wo2w, EE, EE, EP, nullptr);                // Wo2
  k_gemm<<<dim3(12, 1), 256, 0, stream>>>(out2h, EP, Wsm, EP, mha2, EP, EE, EP, bo2, 0);
  k_cast64<<<BB, 256, 0, stream>>>(mha2, mha2h, EE, EP);

  // ---- collapsed scan-2 final step + classifier ----
  k_cast<<<HP, 256, 0, stream>>>(Wbig, Whh1, HH, HH, HP, nullptr);               // Whh1 raw
  k_gemm<<<dim3(37, 1), 256, 0, stream>>>(mha1h, HP, Wbig, HP, u1, HP, HH, HP, nullptr, 1);
  k_lnrow<<<BB, 256, 0, stream>>>(u1, HP, HH, g1, be1, h1nh, nullptr, HP);
  k_cast<<<EP, 256, 0, stream>>>(Wsm, Wih2, EE, HH, HP, nullptr);                // Wih2 raw
  k_gemm<<<dim3(12, 1), 256, 0, stream>>>(h1nh, HP, Wsm, HP, u2, EP, EE, HP, bih2, 0);
  k_cast<<<EP, 256, 0, stream>>>(Wsm, Whh2, EE, EE, EP, nullptr);                // Whh2 raw
  k_gemm<<<dim3(12, 1), 256, 0, stream>>>(mha2h, EP, Wsm, EP, u2, EP, EE, EP, bhh2, 1);
  k_lnrow<<<BB, 256, 0, stream>>>(u2, EP, EE, g2, be2, nullptr, h2nf, EP);
  k_logits<<<BB, 256, 0, stream>>>(h2nf, Wc, bc, outp);
}